// Round 7
// baseline (173.770 us; speedup 1.0000x reference)
//
#include <hip/hip_runtime.h>
#include <math.h>

namespace {
constexpr int B = 8, L = 512, E = 512, H = 8;
constexpr int M = B * L;  // 4096
}

typedef float f32x4 __attribute__((ext_vector_type(4)));
typedef short bf16x8 __attribute__((ext_vector_type(8)));

__device__ inline ushort f2b(float f) {
  unsigned u = __float_as_uint(f);
  u += 0x7FFF + ((u >> 16) & 1);
  return (ushort)(u >> 16);
}
__device__ inline float b2f(ushort h) { return __uint_as_float(((unsigned)h) << 16); }

__device__ inline f32x4 mfma16(bf16x8 a, bf16x8 b, f32x4 c) {
  return __builtin_amdgcn_mfma_f32_16x16x32_bf16(a, b, c, 0, 0, 0);
}

// async global->LDS 16B per lane (LDS dest = wave-uniform base + lane*16)
__device__ __forceinline__ void gl2lds16(const ushort* g, ushort* l) {
  __builtin_amdgcn_global_load_lds(
      (const __attribute__((address_space(1))) void*)g,
      (__attribute__((address_space(3))) void*)l, 16, 0, 0);
}

// Stage NROWS x 64 bf16 tile (row stride ldg elems) into linear LDS [row][64],
// with inverse-XOR-swizzled SOURCE: LDS slot s of row r holds global chunk s^(r&7).
template <int NROWS>
__device__ __forceinline__ void stage64(const ushort* __restrict__ g, int ldg,
                                        ushort* lds, int tid) {
  const int w = tid >> 6, l = tid & 63;
  constexpr int RPW = NROWS / 4;  // rows per wave
  constexpr int NI = RPW / 8;     // 8 rows per instruction
#pragma unroll
  for (int it = 0; it < NI; ++it) {
    const int rbase = w * RPW + it * 8;
    const int row = rbase + (l >> 3);
    const int chunk = (l & 7) ^ (row & 7);
    gl2lds16(g + (size_t)row * ldg + chunk * 8, lds + rbase * 64);
  }
}

// ======== fused prologue: converts + weight transposes + static blend =======
__device__ __forceinline__ void tcvt_body(const float* __restrict__ src,
                                          ushort* __restrict__ dst, int Kd, int Nd,
                                          int kb, int nb, int t, ushort (*T)[33]) {
  const int r = t >> 3, c4 = (t & 7) * 4;
  float4 v = *(const float4*)(src + (size_t)(kb + r) * Nd + nb + c4);
  T[r][c4 + 0] = f2b(v.x); T[r][c4 + 1] = f2b(v.y);
  T[r][c4 + 2] = f2b(v.z); T[r][c4 + 3] = f2b(v.w);
  __syncthreads();
  ushort4 ov = {T[c4 + 0][r], T[c4 + 1][r], T[c4 + 2][r], T[c4 + 3][r]};
  *(ushort4*)(&dst[(size_t)(nb + r) * Kd + kb + c4]) = ov;
}

__global__ __launch_bounds__(256) void prologue_kernel(
    const float* __restrict__ x4e, const float* __restrict__ query,
    const float* __restrict__ Win, const float* __restrict__ Wqkv,
    const float* __restrict__ Wf1, const float* __restrict__ rel,
    const float* __restrict__ resp, const float* __restrict__ ts,
    const float* __restrict__ l1p, const float* __restrict__ l2p,
    const float* __restrict__ l3p, ushort* __restrict__ x4e_bf,
    ushort* __restrict__ qbf, ushort* __restrict__ Wint,
    ushort* __restrict__ Wqkvt, ushort* __restrict__ Wf1t,
    ushort* __restrict__ stat) {
  __shared__ ushort T[32][33];
  const int NB_CVT = (M * 2048 / 4 + M * 512 / 4) / 256;  // 10240
  const int bi = blockIdx.x;
  const int t = threadIdx.x;
  if (bi < NB_CVT) {
    const int N1 = M * 2048 / 4;
    int i = bi * 256 + t;
    if (i < N1) {
      float4 v = ((const float4*)x4e)[i];
      ushort4 o = {f2b(v.x), f2b(v.y), f2b(v.z), f2b(v.w)};
      ((ushort4*)x4e_bf)[i] = o;
    } else {
      int j = i - N1;
      float4 v = ((const float4*)query)[j];
      ushort4 o = {f2b(v.x), f2b(v.y), f2b(v.z), f2b(v.w)};
      ((ushort4*)qbf)[j] = o;
    }
    return;
  }
  if (bi < NB_CVT + 3072) {  // weight transposes
    const int idx = bi - NB_CVT;
    const long long EE = (long long)E * E;
    if (idx < 1024) {
      tcvt_body(Win, Wint, 2048, 512, (idx >> 4) * 32, (idx & 15) * 32, t, T);
    } else if (idx < 2560) {
      const int q = idx - 1024;
      const int z = q >> 8, r = q & 255;
      tcvt_body(Wqkv + z * EE, Wqkvt + z * EE, 512, 512, (r >> 4) * 32, (r & 15) * 32, t, T);
    } else {
      const int q = idx - 2560;
      tcvt_body(Wf1, Wf1t, 1024, 512, (q >> 4) * 32, (q & 15) * 32, t, T);
    }
    return;
  }
  // ---- static blend: c_t*time + c_r*rel + c_s*resp softmaxes -> bf16 ----
  {
    const float l1 = l1p[0], l2 = l2p[0], l3 = l3p[0];
    const float c_t = (1.f - l3) * (1.f - l1) * l2;
    const float c_r = (1.f - l3) * l1;
    const float c_s = l3;
    const int wave = t >> 6, lane = t & 63;
    const int row = (bi - NB_CVT - 3072) * 4 + wave;
    const int qi = row & (L - 1);
    const size_t base = (size_t)row * L;
    float rv[8], sv[8], tv[8];
#pragma unroll
    for (int jj = 0; jj < 8; ++jj) {
      const int k = jj * 64 + lane;
      const float r = rel[base + k];
      const float s = resp[base + k];
      const float tt = ts[base + k];
      const bool fut = (k > qi);
      const float rm = fut ? r : 0.f;
      const float sm = fut ? s : 0.f;
      rv[jj] = (rm == 0.f) ? -1e4f : rm;
      sv[jj] = (sm == 0.f) ? -1e4f : sm;
      tv[jj] = fut ? -INFINITY : __expf(-fabsf(tt));
    }
    float rmax = -INFINITY, smax = -INFINITY, tmax = -INFINITY;
#pragma unroll
    for (int jj = 0; jj < 8; ++jj) {
      rmax = fmaxf(rmax, rv[jj]); smax = fmaxf(smax, sv[jj]); tmax = fmaxf(tmax, tv[jj]);
    }
    for (int off = 1; off < 64; off <<= 1) {
      rmax = fmaxf(rmax, __shfl_xor(rmax, off));
      smax = fmaxf(smax, __shfl_xor(smax, off));
      tmax = fmaxf(tmax, __shfl_xor(tmax, off));
    }
    float rsum = 0.f, ssum = 0.f, tsum = 0.f;
#pragma unroll
    for (int jj = 0; jj < 8; ++jj) {
      rsum += __expf(rv[jj] - rmax); ssum += __expf(sv[jj] - smax); tsum += __expf(tv[jj] - tmax);
    }
    for (int off = 1; off < 64; off <<= 1) {
      rsum += __shfl_xor(rsum, off);
      ssum += __shfl_xor(ssum, off);
      tsum += __shfl_xor(tsum, off);
    }
    const float rinv = c_r / rsum, sinv = c_s / ssum, tinv = c_t / tsum;
#pragma unroll
    for (int jj = 0; jj < 8; ++jj) {
      stat[base + jj * 64 + lane] =
          f2b(__expf(rv[jj] - rmax) * rinv + __expf(sv[jj] - smax) * sinv +
              __expf(tv[jj] - tmax) * tinv);
    }
  }
}

// ------------- 2-phase double-buffered MFMA GEMM ----------------------------
// A:(rows x K) bf16 rm, Wt:(N x K) bf16 rm. BK=64. One barrier per K-tile.
// MODE 1: C0 = bf16 (rows x N)
// MODE 3: layer-0 fused, 4 secs: q0(A->C0), k0(A2->C1), v0(A2->C2 transposed
//         (B,E,L)), q1(A->C3). Wt rows contiguous across secs; bias flat.
// MODE 5: layer-1, 2 secs: k1(A2->C1), v1(A2->C2 transposed).
// MODE 4: split-A: K-tiles 0..7 from A (ld 512), 8..15 from A2 (ld 512)
template <int BM, int MODE, int HAS_BIAS, int ACT>
__global__ __launch_bounds__(256) void gemm2(
    const ushort* __restrict__ A, const ushort* __restrict__ A2,
    const ushort* __restrict__ Wt, const float* __restrict__ bias,
    void* __restrict__ C0, void* __restrict__ C1, void* __restrict__ C2,
    void* __restrict__ C3, int K, int N) {
  __shared__ ushort Als[2][BM * 64];
  __shared__ ushort Bls[2][64 * 64];
  const int tid = threadIdx.x;
  const int l = tid & 63, wv = tid >> 6;
  const int wr = wv >> 1, wc = wv & 1;
  const int g = l >> 4, c = l & 15;
  constexpr int WM = BM / 2;    // wave row span
  constexpr int MFR = WM / 16;  // m-frags per wave
  const int bm = blockIdx.y * BM;
  const int bn64 = blockIdx.x * 64;
  const int sec = (MODE == 3 || MODE == 5) ? (bn64 >> 9) : 0;
  const bool vsec = (MODE == 3 && sec == 2) || (MODE == 5 && sec == 1);

  const ushort* Ause = A;
  if (MODE == 3 && (sec == 1 || sec == 2)) Ause = A2;
  if (MODE == 5) Ause = A2;
  const int ldA = (MODE == 4) ? 512 : K;
  const ushort* Bp = Wt + (size_t)bn64 * K;

  f32x4 acc[MFR][2];
#pragma unroll
  for (int mi = 0; mi < MFR; ++mi)
#pragma unroll
    for (int ni = 0; ni < 2; ++ni) acc[mi][ni] = f32x4{0.f, 0.f, 0.f, 0.f};

#define A_TILE(t) \
  ((MODE == 4) ? ((t) < 8 ? A + (size_t)bm * 512 + (t) * 64 \
                          : A2 + (size_t)bm * 512 + ((t) - 8) * 64) \
               : Ause + (size_t)bm * ldA + (t) * 64)

  stage64<BM>(A_TILE(0), ldA, &Als[0][0], tid);
  stage64<64>(Bp, K, &Bls[0][0], tid);
  __syncthreads();

  const int NT = K >> 6;
  int cur = 0;
  for (int t = 0; t < NT; ++t) {
    if (t + 1 < NT) {
      stage64<BM>(A_TILE(t + 1), ldA, &Als[cur ^ 1][0], tid);
      stage64<64>(Bp + (t + 1) * 64, K, &Bls[cur ^ 1][0], tid);
    }
#pragma unroll
    for (int ks = 0; ks < 2; ++ks) {
      bf16x8 af[MFR], bf_[2];
#pragma unroll
      for (int mi = 0; mi < MFR; ++mi) {
        const int row = wr * WM + mi * 16 + c;
        af[mi] = *(const bf16x8*)(&Als[cur][row * 64 + (((ks * 4 + g) ^ (row & 7)) * 8)]);
      }
#pragma unroll
      for (int ni = 0; ni < 2; ++ni) {
        const int row = wc * 32 + ni * 16 + c;
        bf_[ni] = *(const bf16x8*)(&Bls[cur][row * 64 + (((ks * 4 + g) ^ (row & 7)) * 8)]);
      }
      if (vsec) {
#pragma unroll
        for (int mi = 0; mi < MFR; ++mi)
#pragma unroll
          for (int ni = 0; ni < 2; ++ni)
            acc[mi][ni] = mfma16(bf_[ni], af[mi], acc[mi][ni]);
      } else {
#pragma unroll
        for (int mi = 0; mi < MFR; ++mi)
#pragma unroll
          for (int ni = 0; ni < 2; ++ni)
            acc[mi][ni] = mfma16(af[mi], bf_[ni], acc[mi][ni]);
      }
    }
    __syncthreads();
    cur ^= 1;
  }
#undef A_TILE

  if (vsec) {
    // swapped acc: D rows = E-dim, cols = tokens -> vt (B,E,L)
    const int vbase = (MODE == 3) ? 1024 : 512;
    const int e0 = bn64 - vbase;
#pragma unroll
    for (int ni = 0; ni < 2; ++ni) {
#pragma unroll
      for (int r = 0; r < 4; ++r) {
        const int e = e0 + wc * 32 + ni * 16 + g * 4 + r;
        const float bv = HAS_BIAS ? bias[vbase + e] : 0.f;
#pragma unroll
        for (int mi = 0; mi < MFR; ++mi) {
          const int m = bm + wr * WM + mi * 16 + c;
          const int bb = m >> 9, lt = m & 511;
          ((ushort*)C2)[((size_t)bb * 512 + e) * 512 + lt] = f2b(acc[mi][ni][r] + bv);
        }
      }
    }
  } else {
    ushort* dst = (ushort*)C0;
    int nsub = 0, ldc = N;
    if (MODE == 3 || MODE == 5) {
      dst = (ushort*)((MODE == 5) ? C1 : (sec == 0 ? C0 : (sec == 1 ? C1 : C3)));
      nsub = sec * 512;
      ldc = 512;
    }
#pragma unroll
    for (int ni = 0; ni < 2; ++ni) {
      const int n = bn64 + wc * 32 + ni * 16 + c;
      const float bv = HAS_BIAS ? bias[n] : 0.f;
#pragma unroll
      for (int mi = 0; mi < MFR; ++mi) {
#pragma unroll
        for (int r = 0; r < 4; ++r) {
          const int m = bm + wr * WM + mi * 16 + g * 4 + r;
          float v = acc[mi][ni][r] + bv;
          if (ACT) v = fmaxf(v, 0.f);
          dst[(size_t)m * ldc + (n - nsub)] = f2b(v);
        }
      }
    }
  }
}

// -------- fused flash attention + stat-PV ----------------------------------
// o_exp = sum_{kt<=qt} exp(QK^T/8) V (no-max; scores bounded),
// o_stat = sum_{all kt} stat V.  out = o_exp * c_p / l + o_stat.
// OUTMODE 1: Ov = bf16(out).  OUTMODE 2: Ov = bf16(b2f(prev) + relu(out)).
template <int OUTMODE>
__global__ __launch_bounds__(256) void attn_mfma(
    const ushort* __restrict__ Qg, const ushort* __restrict__ Kg,
    const ushort* __restrict__ Vt, const ushort* __restrict__ Sg,
    const ushort* __restrict__ prev, const float* __restrict__ l1p,
    const float* __restrict__ l2p, const float* __restrict__ l3p,
    void* __restrict__ Ov) {
  __shared__ ushort Qs[64 * 64];
  __shared__ ushort Ps[64 * 64];
  __shared__ ushort Ks[2][64 * 64];
  __shared__ ushort Vs[2][64 * 64];
  __shared__ ushort Ss[2][64 * 64];
  const int qt = 7 - blockIdx.x;  // heavy tiles dispatch first
  const int h = blockIdx.y, b = blockIdx.z;
  const int tid = threadIdx.x, l = tid & 63, w = tid >> 6;
  const int g = l >> 4, c = l & 15;
  const float l1 = l1p[0], l2 = l2p[0], l3 = l3p[0];
  const float c_p = (1.f - l3) * (1.f - l1) * (1.f - l2);
  const int qrow0 = b * L + qt * 64;
  const ushort* Kbase = Kg + (size_t)(b * L) * E + h * 64;
  const ushort* Vbase = Vt + (size_t)(b * E + h * 64) * L;
  const ushort* Sbase = Sg + (size_t)qrow0 * L;  // stat rows for this q-tile

  stage64<64>(Qg + (size_t)qrow0 * E + h * 64, E, Qs, tid);
  stage64<64>(Kbase, E, Ks[0], tid);
  stage64<64>(Vbase, L, Vs[0], tid);
  stage64<64>(Sbase, L, Ss[0], tid);
  __syncthreads();

  f32x4 o[4], ost[4];
#pragma unroll
  for (int dn = 0; dn < 4; ++dn) {
    o[dn] = f32x4{0.f, 0.f, 0.f, 0.f};
    ost[dn] = f32x4{0.f, 0.f, 0.f, 0.f};
  }
  float l_r[4] = {0.f, 0.f, 0.f, 0.f};

  int cur = 0;
  for (int kt = 0; kt < 8; ++kt) {
    if (kt < 7) {  // prefetch next K/V/S tile under compute
      stage64<64>(Kbase + (size_t)(kt + 1) * 64 * E, E, Ks[cur ^ 1], tid);
      stage64<64>(Vbase + (kt + 1) * 64, L, Vs[cur ^ 1], tid);
      stage64<64>(Sbase + (kt + 1) * 64, L, Ss[cur ^ 1], tid);
    }
    const bool causal = (kt <= qt);
    bf16x8 pf[2], sf[2];
    {
      const int row = w * 16 + c;
#pragma unroll
      for (int kq = 0; kq < 2; ++kq)
        sf[kq] = *(const bf16x8*)(&Ss[cur][row * 64 + (((kq * 4 + g) ^ (row & 7)) * 8)]);
    }
    if (causal) {
      // S = Q K^T
      bf16x8 qf[2];
      {
        const int row = w * 16 + c;
#pragma unroll
        for (int kq = 0; kq < 2; ++kq)
          qf[kq] = *(const bf16x8*)(&Qs[row * 64 + (((kq * 4 + g) ^ (row & 7)) * 8)]);
      }
      f32x4 s4[4];
#pragma unroll
      for (int n = 0; n < 4; ++n) s4[n] = f32x4{0.f, 0.f, 0.f, 0.f};
#pragma unroll
      for (int n = 0; n < 4; ++n) {
#pragma unroll
        for (int kq = 0; kq < 2; ++kq) {
          int row = n * 16 + c;
          bf16x8 kf = *(const bf16x8*)(&Ks[cur][row * 64 + (((kq * 4 + g) ^ (row & 7)) * 8)]);
          s4[n] = mfma16(qf[kq], kf, s4[n]);
        }
      }
      // P = exp(S/8) (no max subtraction: |S/8| bounded; masked -> exp(-1e30)=0)
      const bool diag = (kt == qt);
      float pv[4][4];
      float lad[4] = {0.f, 0.f, 0.f, 0.f};
#pragma unroll
      for (int n = 0; n < 4; ++n)
#pragma unroll
        for (int r = 0; r < 4; ++r) {
          float sv = s4[n][r] * 0.125f;
          if (diag && (n * 16 + c) > (w * 16 + g * 4 + r)) sv = -1e30f;
          float p = __expf(sv);
          pv[n][r] = p;
          lad[r] += p;
        }
#pragma unroll
      for (int off = 1; off < 16; off <<= 1)
#pragma unroll
        for (int r = 0; r < 4; ++r) lad[r] += __shfl_xor(lad[r], off);
#pragma unroll
      for (int r = 0; r < 4; ++r) l_r[r] += lad[r];
      // write P (bf16, swizzled) — wave-local rows, no barrier needed
#pragma unroll
      for (int n = 0; n < 4; ++n)
#pragma unroll
        for (int r = 0; r < 4; ++r) {
          int q = w * 16 + g * 4 + r;
          int byt = 32 * n + 2 * c;
          int slot = byt >> 4;
          Ps[q * 64 + ((slot ^ (q & 7)) * 8) + ((byt & 15) >> 1)] = f2b(pv[n][r]);
        }
      {
        const int row = w * 16 + c;
#pragma unroll
        for (int kq = 0; kq < 2; ++kq)
          pf[kq] = *(const bf16x8*)(&Ps[row * 64 + (((kq * 4 + g) ^ (row & 7)) * 8)]);
      }
    }
    // O += P V (causal) and Ost += stat V (always); share V fragments
#pragma unroll
    for (int dn = 0; dn < 4; ++dn) {
#pragma unroll
      for (int kq = 0; kq < 2; ++kq) {
        int row = dn * 16 + c;
        bf16x8 vf = *(const bf16x8*)(&Vs[cur][row * 64 + (((kq * 4 + g) ^ (row & 7)) * 8)]);
        if (causal) o[dn] = mfma16(pf[kq], vf, o[dn]);
        ost[dn] = mfma16(sf[kq], vf, ost[dn]);
      }
    }
    __syncthreads();  // drains prefetch + protects buffer swap
    cur ^= 1;
  }

  float linv[4];
#pragma unroll
  for (int r = 0; r < 4; ++r) linv[r] = c_p / l_r[r];
#pragma unroll
  for (int dn = 0; dn < 4; ++dn) {
#pragma unroll
    for (int r = 0; r < 4; ++r) {
      const size_t row = (size_t)qrow0 + w * 16 + g * 4 + r;
      const int col = h * 64 + dn * 16 + c;
      float v = o[dn][r] * linv[r] + ost[dn][r];
      if (OUTMODE == 1) {
        ((ushort*)Ov)[row * E + col] = f2b(v);
      } else {
        ((ushort*)Ov)[row * E + col] = f2b(b2f(prev[row * E + col]) + fmaxf(v, 0.f));
      }
    }
  }
}

// -------- out[m] = h[m,:].Wf2 + bf2  (4 rows per 256-thread block) --------
__global__ __launch_bounds__(256) void final_dot_kernel(const ushort* __restrict__ hb,
                                                        const float* __restrict__ w,
                                                        const float* __restrict__ b2,
                                                        float* __restrict__ out) {
  const int m = blockIdx.x * 4 + (threadIdx.x >> 6);
  const int lane = threadIdx.x & 63;
  float s = 0.f;
#pragma unroll
  for (int it = 0; it < 2; ++it) {
    const int e = it * 256 + lane * 4;
    ushort4 hv = *(const ushort4*)(hb + (size_t)m * E + e);
    float4 wv = *(const float4*)(w + e);
    s += b2f(hv.x) * wv.x + b2f(hv.y) * wv.y + b2f(hv.z) * wv.z + b2f(hv.w) * wv.w;
  }
  for (int off = 1; off < 64; off <<= 1) s += __shfl_xor(s, off);
  if (lane == 0) out[m] = s + b2[0];
}

extern "C" void kernel_launch(void* const* d_in, const int* in_sizes, int n_in,
                              void* d_out, int out_size, void* d_ws, size_t ws_size,
                              hipStream_t stream) {
  (void)in_sizes; (void)n_in; (void)out_size; (void)ws_size;
  const float* inputs_4e = (const float*)d_in[0];
  const float* query = (const float*)d_in[1];
  const float* rel = (const float*)d_in[2];
  const float* resp = (const float*)d_in[3];
  const float* tsp = (const float*)d_in[4];
  const float* l1p = (const float*)d_in[5];
  const float* l2p = (const float*)d_in[6];
  const float* l3p = (const float*)d_in[7];
  const float* Win = (const float*)d_in[8];
  const float* b_in = (const float*)d_in[9];
  const float* Wqkv = (const float*)d_in[10];
  const float* bqkv = (const float*)d_in[11];
  const float* Wf1 = (const float*)d_in[12];
  const float* bf1 = (const float*)d_in[13];
  const float* Wf2 = (const float*)d_in[14];
  const float* bf2 = (const float*)d_in[15];

  char* ws = (char*)d_ws;
  const size_t MB = 1ull << 20;
  ushort* x4e_bf  = (ushort*)(ws + 0 * MB);   // 16MB; dead after x-GEMM
  ushort* outs2   = (ushort*)(ws + 0 * MB);   // 4MB; written by attn1 (x4e dead)
  ushort* query_bf= (ushort*)(ws + 16 * MB);  // 4MB
  ushort* stat_bf = (ushort*)(ws + 20 * MB);  // 4MB
  ushort* x_bf    = (ushort*)(ws + 24 * MB);  // 4MB; dead after qkv0 -> h_bf
  ushort* h_bf    = (ushort*)(ws + 24 * MB);
  ushort* q_bf    = (ushort*)(ws + 28 * MB);  // 4MB
  ushort* k_bf    = (ushort*)(ws + 32 * MB);  // 4MB
  ushort* vt      = (ushort*)(ws + 36 * MB);  // 4MB (B,E,L)
  ushort* q1_bf   = (ushort*)(ws + 40 * MB);  // 4MB (layer-1 Q, hoisted)
  ushort* outs_bf = (ushort*)(ws + 44 * MB);  // 4MB
  ushort* Wint    = (ushort*)(ws + 48 * MB);  // 2MB (512x2048)
  ushort* Wqkvt   = (ushort*)(ws + 50 * MB);  // 3MB (6x 512x512)
  ushort* Wf1t    = (ushort*)(ws + 53 * MB);  // 1MB (512x1024)

  const long long EE = (long long)E * E;

  // 1) fused prologue: converts + weight transposes + static blend
  const int NB_PRO = (M * 2048 / 4 + M * 512 / 4) / 256 + 3072 + M / 4;
  prologue_kernel<<<NB_PRO, 256, 0, stream>>>(
      inputs_4e, query, Win, Wqkv, Wf1, rel, resp, tsp, l1p, l2p, l3p,
      x4e_bf, query_bf, Wint, Wqkvt, Wf1t, stat_bf);

  // 2) x = relu(x4e @ Win + b_in)   (fully consumes x4e_bf)
  gemm2<64, 1, 1, 1><<<dim3(8, 64), 256, 0, stream>>>(
      x4e_bf, nullptr, Wint, b_in, x_bf, nullptr, nullptr, nullptr, 2048, 512);

  // 3) layer-0 qkv + hoisted q1: secs q0,k0,v0,q1
  gemm2<128, 3, 1, 0><<<dim3(32, 32), 256, 0, stream>>>(
      query_bf, x_bf, Wqkvt, bqkv, q_bf, k_bf, vt, q1_bf, 512, 2048);

  // 4) attention 0 (fused stat-PV)
  const dim3 ga(8, 8, 8);
  attn_mfma<1><<<ga, 256, 0, stream>>>(q_bf, k_bf, vt, stat_bf, nullptr,
                                       l1p, l2p, l3p, outs_bf);

  // 5) layer-1 k,v
  gemm2<128, 5, 1, 0><<<dim3(16, 32), 256, 0, stream>>>(
      query_bf, outs_bf, Wqkvt + 4 * EE, bqkv + 4 * E, nullptr, k_bf, vt, nullptr,
      512, 1024);

  // 6) attention 1 (fused stat-PV; writes outs + relu(attn))
  attn_mfma<2><<<ga, 256, 0, stream>>>(q1_bf, k_bf, vt, stat_bf, outs_bf,
                                       l1p, l2p, l3p, outs2);

  // 7) h = relu([outs2 | query] @ Wf1 + bf1) via split-A GEMM
  gemm2<64, 4, 1, 1><<<dim3(8, 64), 256, 0, stream>>>(
      outs2, query_bf, Wf1t, bf1, h_bf, nullptr, nullptr, nullptr, 1024, 512);

  // 8) out = h @ Wf2 + bf2
  final_dot_kernel<<<M / 4, 256, 0, stream>>>(h_bf, Wf2, bf2, (float*)d_out);
}

// Round 8
// 149.895 us; speedup vs baseline: 1.1593x; 1.1593x over previous
//
#include <hip/hip_runtime.h>
#include <math.h>

namespace {
constexpr int B = 8, L = 512, E = 512, H = 8;
constexpr int M = B * L;  // 4096
}

typedef float f32x4 __attribute__((ext_vector_type(4)));
typedef short bf16x8 __attribute__((ext_vector_type(8)));

__device__ inline ushort f2b(float f) {
  unsigned u = __float_as_uint(f);
  u += 0x7FFF + ((u >> 16) & 1);
  return (ushort)(u >> 16);
}
__device__ inline float b2f(ushort h) { return __uint_as_float(((unsigned)h) << 16); }

__device__ inline f32x4 mfma16(bf16x8 a, bf16x8 b, f32x4 c) {
  return __builtin_amdgcn_mfma_f32_16x16x32_bf16(a, b, c, 0, 0, 0);
}

// async global->LDS 16B per lane (LDS dest = wave-uniform base + lane*16)
__device__ __forceinline__ void gl2lds16(const ushort* g, ushort* l) {
  __builtin_amdgcn_global_load_lds(
      (const __attribute__((address_space(1))) void*)g,
      (__attribute__((address_space(3))) void*)l, 16, 0, 0);
}

// Stage NROWS x 64 bf16 tile (row stride ldg elems) into linear LDS [row][64],
// with inverse-XOR-swizzled SOURCE: LDS slot s of row r holds global chunk s^(r&7).
template <int NROWS>
__device__ __forceinline__ void stage64(const ushort* __restrict__ g, int ldg,
                                        ushort* lds, int tid) {
  const int w = tid >> 6, l = tid & 63;
  constexpr int RPW = NROWS / 4;  // rows per wave
  constexpr int NI = RPW / 8;     // 8 rows per instruction
#pragma unroll
  for (int it = 0; it < NI; ++it) {
    const int rbase = w * RPW + it * 8;
    const int row = rbase + (l >> 3);
    const int chunk = (l & 7) ^ (row & 7);
    gl2lds16(g + (size_t)row * ldg + chunk * 8, lds + rbase * 64);
  }
}

// ======== fused prologue: converts + weight transposes + static blend =======
__device__ __forceinline__ void tcvt_body(const float* __restrict__ src,
                                          ushort* __restrict__ dst, int Kd, int Nd,
                                          int kb, int nb, int t, ushort (*T)[33]) {
  const int r = t >> 3, c4 = (t & 7) * 4;
  float4 v = *(const float4*)(src + (size_t)(kb + r) * Nd + nb + c4);
  T[r][c4 + 0] = f2b(v.x); T[r][c4 + 1] = f2b(v.y);
  T[r][c4 + 2] = f2b(v.z); T[r][c4 + 3] = f2b(v.w);
  __syncthreads();
  ushort4 ov = {T[c4 + 0][r], T[c4 + 1][r], T[c4 + 2][r], T[c4 + 3][r]};
  *(ushort4*)(&dst[(size_t)(nb + r) * Kd + kb + c4]) = ov;
}

__global__ __launch_bounds__(256) void prologue_kernel(
    const float* __restrict__ x4e, const float* __restrict__ query,
    const float* __restrict__ Win, const float* __restrict__ Wqkv,
    const float* __restrict__ Wf1, const float* __restrict__ rel,
    const float* __restrict__ resp, const float* __restrict__ ts,
    const float* __restrict__ l1p, const float* __restrict__ l2p,
    const float* __restrict__ l3p, ushort* __restrict__ x4e_bf,
    ushort* __restrict__ qbf, ushort* __restrict__ Wint,
    ushort* __restrict__ Wqkvt, ushort* __restrict__ Wf1t,
    ushort* __restrict__ stat) {
  __shared__ ushort T[32][33];
  const int NB_CVT = (M * 2048 / 4 + M * 512 / 4) / 256;  // 10240
  const int bi = blockIdx.x;
  const int t = threadIdx.x;
  if (bi < NB_CVT) {
    const int N1 = M * 2048 / 4;
    int i = bi * 256 + t;
    if (i < N1) {
      float4 v = ((const float4*)x4e)[i];
      ushort4 o = {f2b(v.x), f2b(v.y), f2b(v.z), f2b(v.w)};
      ((ushort4*)x4e_bf)[i] = o;
    } else {
      int j = i - N1;
      float4 v = ((const float4*)query)[j];
      ushort4 o = {f2b(v.x), f2b(v.y), f2b(v.z), f2b(v.w)};
      ((ushort4*)qbf)[j] = o;
    }
    return;
  }
  if (bi < NB_CVT + 3072) {  // weight transposes
    const int idx = bi - NB_CVT;
    const long long EE = (long long)E * E;
    if (idx < 1024) {
      tcvt_body(Win, Wint, 2048, 512, (idx >> 4) * 32, (idx & 15) * 32, t, T);
    } else if (idx < 2560) {
      const int q = idx - 1024;
      const int z = q >> 8, r = q & 255;
      tcvt_body(Wqkv + z * EE, Wqkvt + z * EE, 512, 512, (r >> 4) * 32, (r & 15) * 32, t, T);
    } else {
      const int q = idx - 2560;
      tcvt_body(Wf1, Wf1t, 1024, 512, (q >> 4) * 32, (q & 15) * 32, t, T);
    }
    return;
  }
  // ---- static blend: c_t*time + c_r*rel + c_s*resp softmaxes -> bf16 ----
  {
    const float l1 = l1p[0], l2 = l2p[0], l3 = l3p[0];
    const float c_t = (1.f - l3) * (1.f - l1) * l2;
    const float c_r = (1.f - l3) * l1;
    const float c_s = l3;
    const int wave = t >> 6, lane = t & 63;
    const int row = (bi - NB_CVT - 3072) * 4 + wave;
    const int qi = row & (L - 1);
    const size_t base = (size_t)row * L;
    float rv[8], sv[8], tv[8];
#pragma unroll
    for (int jj = 0; jj < 8; ++jj) {
      const int k = jj * 64 + lane;
      const float r = rel[base + k];
      const float s = resp[base + k];
      const float tt = ts[base + k];
      const bool fut = (k > qi);
      const float rm = fut ? r : 0.f;
      const float sm = fut ? s : 0.f;
      rv[jj] = (rm == 0.f) ? -1e4f : rm;
      sv[jj] = (sm == 0.f) ? -1e4f : sm;
      tv[jj] = fut ? -INFINITY : __expf(-fabsf(tt));
    }
    float rmax = -INFINITY, smax = -INFINITY, tmax = -INFINITY;
#pragma unroll
    for (int jj = 0; jj < 8; ++jj) {
      rmax = fmaxf(rmax, rv[jj]); smax = fmaxf(smax, sv[jj]); tmax = fmaxf(tmax, tv[jj]);
    }
    for (int off = 1; off < 64; off <<= 1) {
      rmax = fmaxf(rmax, __shfl_xor(rmax, off));
      smax = fmaxf(smax, __shfl_xor(smax, off));
      tmax = fmaxf(tmax, __shfl_xor(tmax, off));
    }
    float rsum = 0.f, ssum = 0.f, tsum = 0.f;
#pragma unroll
    for (int jj = 0; jj < 8; ++jj) {
      rsum += __expf(rv[jj] - rmax); ssum += __expf(sv[jj] - smax); tsum += __expf(tv[jj] - tmax);
    }
    for (int off = 1; off < 64; off <<= 1) {
      rsum += __shfl_xor(rsum, off);
      ssum += __shfl_xor(ssum, off);
      tsum += __shfl_xor(tsum, off);
    }
    const float rinv = c_r / rsum, sinv = c_s / ssum, tinv = c_t / tsum;
#pragma unroll
    for (int jj = 0; jj < 8; ++jj) {
      stat[base + jj * 64 + lane] =
          f2b(__expf(rv[jj] - rmax) * rinv + __expf(sv[jj] - smax) * sinv +
              __expf(tv[jj] - tmax) * tinv);
    }
  }
}

// ------------- 2-phase double-buffered MFMA GEMM ----------------------------
// A:(rows x K) bf16 rm, Wt:(N x K) bf16 rm. BK=64. One barrier per K-tile.
// MODE 1: C0 = bf16 (rows x N), batched via sA/sW/sC (blockIdx.z)
// MODE 3: layer-0 fused, 4 secs: q0(A->C0), k0(A2->C1), v0(A2->C2 transposed
//         (B,E,L)), q1(A->C3). Wt rows contiguous across secs; bias flat.
// MODE 5: layer-1, 2 secs: k1(A2->C1), v1(A2->C2 transposed).
// MODE 4: split-A: K-tiles 0..7 from A (ld 512), 8..15 from A2 (ld 512)
template <int BM, int MODE, int HAS_BIAS, int ACT>
__global__ __launch_bounds__(256) void gemm2(
    const ushort* __restrict__ A, const ushort* __restrict__ A2,
    const ushort* __restrict__ Wt, const float* __restrict__ bias,
    void* __restrict__ C0, void* __restrict__ C1, void* __restrict__ C2,
    void* __restrict__ C3, int K, int N,
    long long sA, long long sW, long long sC) {
  __shared__ ushort Als[2][BM * 64];
  __shared__ ushort Bls[2][64 * 64];
  const int tid = threadIdx.x;
  const int l = tid & 63, wv = tid >> 6;
  const int wr = wv >> 1, wc = wv & 1;
  const int g = l >> 4, c = l & 15;
  constexpr int WM = BM / 2;    // wave row span
  constexpr int MFR = WM / 16;  // m-frags per wave
  const int bm = blockIdx.y * BM;
  const int bn64 = blockIdx.x * 64;
  const int sec = (MODE == 3 || MODE == 5) ? (bn64 >> 9) : 0;
  const bool vsec = (MODE == 3 && sec == 2) || (MODE == 5 && sec == 1);

  const ushort* Ause = A;
  const ushort* Wuse = Wt;
  if (MODE == 3 && (sec == 1 || sec == 2)) Ause = A2;
  if (MODE == 5) Ause = A2;
  if (MODE == 1) {
    Ause += (size_t)blockIdx.z * sA;
    Wuse += (size_t)blockIdx.z * sW;
  }
  const int ldA = (MODE == 4) ? 512 : K;
  const ushort* Bp = Wuse + (size_t)bn64 * K;

  f32x4 acc[MFR][2];
#pragma unroll
  for (int mi = 0; mi < MFR; ++mi)
#pragma unroll
    for (int ni = 0; ni < 2; ++ni) acc[mi][ni] = f32x4{0.f, 0.f, 0.f, 0.f};

#define A_TILE(t) \
  ((MODE == 4) ? ((t) < 8 ? A + (size_t)bm * 512 + (t) * 64 \
                          : A2 + (size_t)bm * 512 + ((t) - 8) * 64) \
               : Ause + (size_t)bm * ldA + (t) * 64)

  stage64<BM>(A_TILE(0), ldA, &Als[0][0], tid);
  stage64<64>(Bp, K, &Bls[0][0], tid);
  __syncthreads();

  const int NT = K >> 6;
  int cur = 0;
  for (int t = 0; t < NT; ++t) {
    if (t + 1 < NT) {
      stage64<BM>(A_TILE(t + 1), ldA, &Als[cur ^ 1][0], tid);
      stage64<64>(Bp + (t + 1) * 64, K, &Bls[cur ^ 1][0], tid);
    }
#pragma unroll
    for (int ks = 0; ks < 2; ++ks) {
      bf16x8 af[MFR], bf_[2];
#pragma unroll
      for (int mi = 0; mi < MFR; ++mi) {
        const int row = wr * WM + mi * 16 + c;
        af[mi] = *(const bf16x8*)(&Als[cur][row * 64 + (((ks * 4 + g) ^ (row & 7)) * 8)]);
      }
#pragma unroll
      for (int ni = 0; ni < 2; ++ni) {
        const int row = wc * 32 + ni * 16 + c;
        bf_[ni] = *(const bf16x8*)(&Bls[cur][row * 64 + (((ks * 4 + g) ^ (row & 7)) * 8)]);
      }
      if (vsec) {
#pragma unroll
        for (int mi = 0; mi < MFR; ++mi)
#pragma unroll
          for (int ni = 0; ni < 2; ++ni)
            acc[mi][ni] = mfma16(bf_[ni], af[mi], acc[mi][ni]);
      } else {
#pragma unroll
        for (int mi = 0; mi < MFR; ++mi)
#pragma unroll
          for (int ni = 0; ni < 2; ++ni)
            acc[mi][ni] = mfma16(af[mi], bf_[ni], acc[mi][ni]);
      }
    }
    __syncthreads();
    cur ^= 1;
  }
#undef A_TILE

  if (vsec) {
    // swapped acc: D rows = E-dim, cols = tokens -> vt (B,E,L)
    const int vbase = (MODE == 3) ? 1024 : 512;
    const int e0 = bn64 - vbase;
#pragma unroll
    for (int ni = 0; ni < 2; ++ni) {
#pragma unroll
      for (int r = 0; r < 4; ++r) {
        const int e = e0 + wc * 32 + ni * 16 + g * 4 + r;
        const float bv = HAS_BIAS ? bias[vbase + e] : 0.f;
#pragma unroll
        for (int mi = 0; mi < MFR; ++mi) {
          const int m = bm + wr * WM + mi * 16 + c;
          const int bb = m >> 9, lt = m & 511;
          ((ushort*)C2)[((size_t)bb * 512 + e) * 512 + lt] = f2b(acc[mi][ni][r] + bv);
        }
      }
    }
  } else {
    ushort* dst = (ushort*)C0;
    int nsub = 0, ldc = N;
    if (MODE == 3 || MODE == 5) {
      dst = (ushort*)((MODE == 5) ? C1 : (sec == 0 ? C0 : (sec == 1 ? C1 : C3)));
      nsub = sec * 512;
      ldc = 512;
    } else if (MODE == 1) {
      dst += (size_t)blockIdx.z * sC;
    }
#pragma unroll
    for (int ni = 0; ni < 2; ++ni) {
      const int n = bn64 + wc * 32 + ni * 16 + c;
      const float bv = HAS_BIAS ? bias[n] : 0.f;
#pragma unroll
      for (int mi = 0; mi < MFR; ++mi) {
#pragma unroll
        for (int r = 0; r < 4; ++r) {
          const int m = bm + wr * WM + mi * 16 + g * 4 + r;
          float v = acc[mi][ni][r] + bv;
          if (ACT) v = fmaxf(v, 0.f);
          dst[(size_t)m * ldc + (n - nsub)] = f2b(v);
        }
      }
    }
  }
}

// -------- flash attention (causal exp part, no-max: scores bounded) --------
// O = (c_p/l)*sum exp(S) V + ostat.
// OUTMODE 1: Ov(M,E) bf16 = result.
// OUTMODE 2: Ov(M,E) bf16 = b2f(prev) + relu(result)
template <int OUTMODE>
__global__ __launch_bounds__(256) void attn_mfma(
    const ushort* __restrict__ Qg, const ushort* __restrict__ Kg,
    const ushort* __restrict__ Vt, const ushort* __restrict__ OstatB,
    const ushort* __restrict__ prev, const float* __restrict__ l1p,
    const float* __restrict__ l2p, const float* __restrict__ l3p,
    void* __restrict__ Ov) {
  __shared__ ushort Qs[64 * 64];
  __shared__ ushort Ps[64 * 64];
  __shared__ ushort Ks[2][64 * 64];
  __shared__ ushort Vs[2][64 * 64];
  const int qt = 7 - blockIdx.x;  // heavy tiles dispatch first
  const int h = blockIdx.y, b = blockIdx.z;
  const int tid = threadIdx.x, l = tid & 63, w = tid >> 6;
  const int g = l >> 4, c = l & 15;
  const float l1 = l1p[0], l2 = l2p[0], l3 = l3p[0];
  const float c_p = (1.f - l3) * (1.f - l1) * (1.f - l2);
  const int qrow0 = b * L + qt * 64;
  const ushort* Kbase = Kg + (size_t)(b * L) * E + h * 64;
  const ushort* Vbase = Vt + (size_t)(b * E + h * 64) * L;

  stage64<64>(Qg + (size_t)qrow0 * E + h * 64, E, Qs, tid);
  stage64<64>(Kbase, E, Ks[0], tid);
  stage64<64>(Vbase, L, Vs[0], tid);
  __syncthreads();

  f32x4 o[4];
#pragma unroll
  for (int dn = 0; dn < 4; ++dn) o[dn] = f32x4{0.f, 0.f, 0.f, 0.f};
  float l_r[4] = {0.f, 0.f, 0.f, 0.f};

  int cur = 0;
  for (int kt = 0; kt <= qt; ++kt) {
    if (kt < qt) {  // prefetch next K/V tile under compute
      stage64<64>(Kbase + (size_t)(kt + 1) * 64 * E, E, Ks[cur ^ 1], tid);
      stage64<64>(Vbase + (kt + 1) * 64, L, Vs[cur ^ 1], tid);
    }
    // S = Q K^T
    bf16x8 qf[2];
#pragma unroll
    for (int kq = 0; kq < 2; ++kq) {
      int row = w * 16 + c;
      qf[kq] = *(const bf16x8*)(&Qs[row * 64 + (((kq * 4 + g) ^ (row & 7)) * 8)]);
    }
    f32x4 s4[4];
#pragma unroll
    for (int n = 0; n < 4; ++n) s4[n] = f32x4{0.f, 0.f, 0.f, 0.f};
#pragma unroll
    for (int n = 0; n < 4; ++n) {
#pragma unroll
      for (int kq = 0; kq < 2; ++kq) {
        int row = n * 16 + c;
        bf16x8 kf = *(const bf16x8*)(&Ks[cur][row * 64 + (((kq * 4 + g) ^ (row & 7)) * 8)]);
        s4[n] = mfma16(qf[kq], kf, s4[n]);
      }
    }
    // P = exp(S/8) (no max subtraction: |S/8| bounded; masked -> exp(-1e30)=0)
    const bool diag = (kt == qt);
    float pv[4][4];
    float lad[4] = {0.f, 0.f, 0.f, 0.f};
#pragma unroll
    for (int n = 0; n < 4; ++n)
#pragma unroll
      for (int r = 0; r < 4; ++r) {
        float sv = s4[n][r] * 0.125f;
        if (diag && (n * 16 + c) > (w * 16 + g * 4 + r)) sv = -1e30f;
        float p = __expf(sv);
        pv[n][r] = p;
        lad[r] += p;
      }
#pragma unroll
    for (int off = 1; off < 16; off <<= 1)
#pragma unroll
      for (int r = 0; r < 4; ++r) lad[r] += __shfl_xor(lad[r], off);
#pragma unroll
    for (int r = 0; r < 4; ++r) l_r[r] += lad[r];
    // write P (bf16, swizzled) — wave-local rows, no barrier needed
#pragma unroll
    for (int n = 0; n < 4; ++n)
#pragma unroll
      for (int r = 0; r < 4; ++r) {
        int q = w * 16 + g * 4 + r;
        int byt = 32 * n + 2 * c;
        int slot = byt >> 4;
        Ps[q * 64 + ((slot ^ (q & 7)) * 8) + ((byt & 15) >> 1)] = f2b(pv[n][r]);
      }
    // O += P V
    bf16x8 pf[2];
#pragma unroll
    for (int kq = 0; kq < 2; ++kq) {
      int row = w * 16 + c;
      pf[kq] = *(const bf16x8*)(&Ps[row * 64 + (((kq * 4 + g) ^ (row & 7)) * 8)]);
    }
#pragma unroll
    for (int dn = 0; dn < 4; ++dn) {
#pragma unroll
      for (int kq = 0; kq < 2; ++kq) {
        int row = dn * 16 + c;
        bf16x8 vf = *(const bf16x8*)(&Vs[cur][row * 64 + (((kq * 4 + g) ^ (row & 7)) * 8)]);
        o[dn] = mfma16(pf[kq], vf, o[dn]);
      }
    }
    __syncthreads();  // drains prefetch (vmcnt) + protects buffer swap
    cur ^= 1;
  }

  float linv[4];
#pragma unroll
  for (int r = 0; r < 4; ++r) linv[r] = c_p / l_r[r];
#pragma unroll
  for (int dn = 0; dn < 4; ++dn) {
#pragma unroll
    for (int r = 0; r < 4; ++r) {
      const size_t row = (size_t)qrow0 + w * 16 + g * 4 + r;
      const int col = h * 64 + dn * 16 + c;
      float v = o[dn][r] * linv[r] + b2f(OstatB[row * E + col]);
      if (OUTMODE == 1) {
        ((ushort*)Ov)[row * E + col] = f2b(v);
      } else {
        ((ushort*)Ov)[row * E + col] = f2b(b2f(prev[row * E + col]) + fmaxf(v, 0.f));
      }
    }
  }
}

// -------- out[m] = h[m,:].Wf2 + bf2  (4 rows per 256-thread block) --------
__global__ __launch_bounds__(256) void final_dot_kernel(const ushort* __restrict__ hb,
                                                        const float* __restrict__ w,
                                                        const float* __restrict__ b2,
                                                        float* __restrict__ out) {
  const int m = blockIdx.x * 4 + (threadIdx.x >> 6);
  const int lane = threadIdx.x & 63;
  float s = 0.f;
#pragma unroll
  for (int it = 0; it < 2; ++it) {
    const int e = it * 256 + lane * 4;
    ushort4 hv = *(const ushort4*)(hb + (size_t)m * E + e);
    float4 wv = *(const float4*)(w + e);
    s += b2f(hv.x) * wv.x + b2f(hv.y) * wv.y + b2f(hv.z) * wv.z + b2f(hv.w) * wv.w;
  }
  for (int off = 1; off < 64; off <<= 1) s += __shfl_xor(s, off);
  if (lane == 0) out[m] = s + b2[0];
}

extern "C" void kernel_launch(void* const* d_in, const int* in_sizes, int n_in,
                              void* d_out, int out_size, void* d_ws, size_t ws_size,
                              hipStream_t stream) {
  (void)in_sizes; (void)n_in; (void)out_size; (void)ws_size;
  const float* inputs_4e = (const float*)d_in[0];
  const float* query = (const float*)d_in[1];
  const float* rel = (const float*)d_in[2];
  const float* resp = (const float*)d_in[3];
  const float* tsp = (const float*)d_in[4];
  const float* l1p = (const float*)d_in[5];
  const float* l2p = (const float*)d_in[6];
  const float* l3p = (const float*)d_in[7];
  const float* Win = (const float*)d_in[8];
  const float* b_in = (const float*)d_in[9];
  const float* Wqkv = (const float*)d_in[10];
  const float* bqkv = (const float*)d_in[11];
  const float* Wf1 = (const float*)d_in[12];
  const float* bf1 = (const float*)d_in[13];
  const float* Wf2 = (const float*)d_in[14];
  const float* bf2 = (const float*)d_in[15];

  char* ws = (char*)d_ws;
  const size_t MB = 1ull << 20;
  ushort* x4e_bf  = (ushort*)(ws + 0 * MB);   // 16MB; dead after x-GEMM
  ushort* outs2   = (ushort*)(ws + 0 * MB);   // 4MB; written by attn1 (x4e dead)
  ushort* ostat   = (ushort*)(ws + 4 * MB);   // 4MB; written by stat-GEMMs (x4e dead)
  ushort* query_bf= (ushort*)(ws + 16 * MB);  // 4MB
  ushort* stat_bf = (ushort*)(ws + 20 * MB);  // 4MB
  ushort* x_bf    = (ushort*)(ws + 24 * MB);  // 4MB; dead after qkv0 -> h_bf
  ushort* h_bf    = (ushort*)(ws + 24 * MB);
  ushort* q_bf    = (ushort*)(ws + 28 * MB);  // 4MB
  ushort* k_bf    = (ushort*)(ws + 32 * MB);  // 4MB
  ushort* vt      = (ushort*)(ws + 36 * MB);  // 4MB (B,E,L)
  ushort* q1_bf   = (ushort*)(ws + 40 * MB);  // 4MB (layer-1 Q, hoisted)
  ushort* outs_bf = (ushort*)(ws + 44 * MB);  // 4MB
  ushort* Wint    = (ushort*)(ws + 48 * MB);  // 2MB (512x2048)
  ushort* Wqkvt   = (ushort*)(ws + 50 * MB);  // 3MB (6x 512x512)
  ushort* Wf1t    = (ushort*)(ws + 53 * MB);  // 1MB (512x1024)

  const long long EE = (long long)E * E;
  const long long LLs = (long long)L * L;
  const long long ELs = (long long)E * L;

  // 1) fused prologue: converts + weight transposes + static blend
  const int NB_PRO = (M * 2048 / 4 + M * 512 / 4) / 256 + 3072 + M / 4;
  prologue_kernel<<<NB_PRO, 256, 0, stream>>>(
      inputs_4e, query, Win, Wqkv, Wf1, rel, resp, tsp, l1p, l2p, l3p,
      x4e_bf, query_bf, Wint, Wqkvt, Wf1t, stat_bf);

  // 2) x = relu(x4e @ Win + b_in)   (fully consumes x4e_bf)
  gemm2<64, 1, 1, 1><<<dim3(8, 64), 256, 0, stream>>>(
      x4e_bf, nullptr, Wint, b_in, x_bf, nullptr, nullptr, nullptr, 2048, 512, 0, 0, 0);

  // 3) layer-0 qkv + hoisted q1: secs q0,k0,v0,q1
  gemm2<128, 3, 1, 0><<<dim3(32, 32), 256, 0, stream>>>(
      query_bf, x_bf, Wqkvt, bqkv, q_bf, k_bf, vt, q1_bf, 512, 2048, 0, 0, 0);

  // 4) ostat0 = stat @ V0 (batched per b; vt as N x K operand)
  gemm2<64, 1, 0, 0><<<dim3(8, 8, 8), 256, 0, stream>>>(
      stat_bf, nullptr, vt, nullptr, ostat, nullptr, nullptr, nullptr,
      512, 512, LLs, ELs, ELs);

  // 5) attention 0
  const dim3 ga(8, 8, 8);
  attn_mfma<1><<<ga, 256, 0, stream>>>(q_bf, k_bf, vt, ostat, nullptr,
                                       l1p, l2p, l3p, outs_bf);

  // 6) layer-1 k,v
  gemm2<128, 5, 1, 0><<<dim3(16, 32), 256, 0, stream>>>(
      query_bf, outs_bf, Wqkvt + 4 * EE, bqkv + 4 * E, nullptr, k_bf, vt, nullptr,
      512, 1024, 0, 0, 0);

  // 7) ostat1 = stat @ V1
  gemm2<64, 1, 0, 0><<<dim3(8, 8, 8), 256, 0, stream>>>(
      stat_bf, nullptr, vt, nullptr, ostat, nullptr, nullptr, nullptr,
      512, 512, LLs, ELs, ELs);

  // 8) attention 1 (writes outs + relu(attn))
  attn_mfma<2><<<ga, 256, 0, stream>>>(q1_bf, k_bf, vt, ostat, outs_bf,
                                       l1p, l2p, l3p, outs2);

  // 9) h = relu([outs2 | query] @ Wf1 + bf1) via split-A GEMM
  gemm2<64, 4, 1, 1><<<dim3(8, 64), 256, 0, stream>>>(
      outs2, query_bf, Wf1t, bf1, h_bf, nullptr, nullptr, nullptr, 1024, 512, 0, 0, 0);

  // 10) out = h @ Wf2 + bf2
  final_dot_kernel<<<M / 4, 256, 0, stream>>>(h_bf, Wf2, bf2, (float*)d_out);
}

// Round 9
// 142.352 us; speedup vs baseline: 1.2207x; 1.0530x over previous
//
#include <hip/hip_runtime.h>
#include <math.h>

namespace {
constexpr int B = 8, L = 512, E = 512, H = 8;
constexpr int M = B * L;  // 4096
}

typedef float f32x4 __attribute__((ext_vector_type(4)));
typedef short bf16x8 __attribute__((ext_vector_type(8)));

__device__ inline ushort f2b(float f) {
  unsigned u = __float_as_uint(f);
  u += 0x7FFF + ((u >> 16) & 1);
  return (ushort)(u >> 16);
}
__device__ inline float b2f(ushort h) { return __uint_as_float(((unsigned)h) << 16); }

__device__ inline f32x4 mfma16(bf16x8 a, bf16x8 b, f32x4 c) {
  return __builtin_amdgcn_mfma_f32_16x16x32_bf16(a, b, c, 0, 0, 0);
}

// async global->LDS 16B per lane (LDS dest = wave-uniform base + lane*16)
__device__ __forceinline__ void gl2lds16(const ushort* g, ushort* l) {
  __builtin_amdgcn_global_load_lds(
      (const __attribute__((address_space(1))) void*)g,
      (__attribute__((address_space(3))) void*)l, 16, 0, 0);
}

// Stage NROWS x 64 bf16 tile into linear LDS [row][64] with inverse-XOR-swizzled
// SOURCE: LDS slot s of row r holds global chunk s^(r&7).
template <int NROWS>
__device__ __forceinline__ void stage64(const ushort* __restrict__ g, int ldg,
                                        ushort* lds, int tid) {
  const int w = tid >> 6, l = tid & 63;
  constexpr int RPW = NROWS / 4;
  constexpr int NI = RPW / 8;
#pragma unroll
  for (int it = 0; it < NI; ++it) {
    const int rbase = w * RPW + it * 8;
    const int row = rbase + (l >> 3);
    const int chunk = (l & 7) ^ (row & 7);
    gl2lds16(g + (size_t)row * ldg + chunk * 8, lds + rbase * 64);
  }
}

// reg-staged combine of bf16 buffers (row stride 512) into swizzled LDS tile.
// NBUF=2: b0+b1.  NBUF=4: (b0+b1)+relu(b2+b3).
template <int BM, int NBUF>
__device__ __forceinline__ void stage_comb(const ushort* b0, const ushort* b1,
                                           const ushort* b2, const ushort* b3,
                                           ushort* lds, int tid) {
#pragma unroll
  for (int it = 0; it < BM / 32; ++it) {
    const int row = (tid >> 3) + it * 32;
    const int slot = tid & 7;
    const size_t off = (size_t)row * 512 + slot * 8;
    union Uu { uint4 u; ushort s[8]; } va, vb, vc, vd, vo;
    va.u = *(const uint4*)(b0 + off);
    vb.u = *(const uint4*)(b1 + off);
    if (NBUF == 4) {
      vc.u = *(const uint4*)(b2 + off);
      vd.u = *(const uint4*)(b3 + off);
    }
#pragma unroll
    for (int e = 0; e < 8; ++e) {
      float f = b2f(va.s[e]) + b2f(vb.s[e]);
      if (NBUF == 4) f += fmaxf(b2f(vc.s[e]) + b2f(vd.s[e]), 0.f);
      vo.s[e] = f2b(f);
    }
    *(uint4*)(&lds[row * 64 + ((slot ^ (row & 7)) * 8)]) = vo.u;
  }
}

// ------------- 2-phase double-buffered MFMA GEMM core -----------------------
// A:(rows x K) bf16 rm, Wt:(N x K) bf16 rm. BK=64, one barrier per K-tile.
// MODE 1: C0 (rows x N).  MODE 3: qkv0 4 secs q0|k0|v0(T)|q1.
// MODE 5: kv1 2 secs k1|v1(T).  MODE 4: split-A f1.
// STAGEA 0: gl2lds.  2: A-tiles = comb2(A,A2).  4: t<8 comb4(A,A2,A3,A4), t>=8 Aq.
template <int BM, int MODE, int HAS_BIAS, int ACT, int STAGEA>
__device__ __forceinline__ void dev_gemm(
    ushort* lds, int bxx, int by, const ushort* A, const ushort* A2,
    const ushort* A3, const ushort* A4, const ushort* Aq,
    const ushort* Wt, const float* bias, ushort* C0, ushort* C1, ushort* C2,
    ushort* C3, int K, int N) {
  ushort* Als = lds;
  ushort* Bls = lds + 2 * BM * 64;
  const int tid = threadIdx.x;
  const int l = tid & 63, wv = tid >> 6;
  const int wr = wv >> 1, wc = wv & 1;
  const int g = l >> 4, c = l & 15;
  constexpr int WM = BM / 2;
  constexpr int MFR = WM / 16;
  const int bm = by * BM;
  const int bn64 = bxx * 64;
  const int sec = (MODE == 3 || MODE == 5) ? (bn64 >> 9) : 0;
  const bool vsec = (MODE == 3 && sec == 2) || (MODE == 5 && sec == 1);

  const ushort* Ause = A;
  if (MODE == 3 && (sec == 1 || sec == 2)) Ause = A2;
  const int ldA = K;
  const ushort* Bp = Wt + (size_t)bn64 * K;

  f32x4 acc[MFR][2];
#pragma unroll
  for (int mi = 0; mi < MFR; ++mi)
#pragma unroll
    for (int ni = 0; ni < 2; ++ni) acc[mi][ni] = f32x4{0.f, 0.f, 0.f, 0.f};

  auto stageA = [&](int t, int buf) {
    ushort* dst = Als + buf * BM * 64;
    if (STAGEA == 0) {
      stage64<BM>(Ause + (size_t)bm * ldA + t * 64, ldA, dst, tid);
    } else if (STAGEA == 2) {
      stage_comb<BM, 2>(A + (size_t)bm * 512 + t * 64,
                        A2 + (size_t)bm * 512 + t * 64, nullptr, nullptr, dst, tid);
    } else {
      if (t < 8)
        stage_comb<BM, 4>(A + (size_t)bm * 512 + t * 64,
                          A2 + (size_t)bm * 512 + t * 64,
                          A3 + (size_t)bm * 512 + t * 64,
                          A4 + (size_t)bm * 512 + t * 64, dst, tid);
      else
        stage64<BM>(Aq + (size_t)bm * 512 + (t - 8) * 64, 512, dst, tid);
    }
  };

  stageA(0, 0);
  stage64<64>(Bp, K, Bls, tid);
  __syncthreads();

  const int NT = K >> 6;
  int cur = 0;
  for (int t = 0; t < NT; ++t) {
    if (t + 1 < NT) {
      stageA(t + 1, cur ^ 1);
      stage64<64>(Bp + (t + 1) * 64, K, Bls + (cur ^ 1) * 64 * 64, tid);
    }
#pragma unroll
    for (int ks = 0; ks < 2; ++ks) {
      bf16x8 af[MFR], bf_[2];
#pragma unroll
      for (int mi = 0; mi < MFR; ++mi) {
        const int row = wr * WM + mi * 16 + c;
        af[mi] = *(const bf16x8*)(&Als[cur * BM * 64 + row * 64 +
                                       (((ks * 4 + g) ^ (row & 7)) * 8)]);
      }
#pragma unroll
      for (int ni = 0; ni < 2; ++ni) {
        const int row = wc * 32 + ni * 16 + c;
        bf_[ni] = *(const bf16x8*)(&Bls[cur * 64 * 64 + row * 64 +
                                        (((ks * 4 + g) ^ (row & 7)) * 8)]);
      }
      if (vsec) {
#pragma unroll
        for (int mi = 0; mi < MFR; ++mi)
#pragma unroll
          for (int ni = 0; ni < 2; ++ni)
            acc[mi][ni] = mfma16(bf_[ni], af[mi], acc[mi][ni]);
      } else {
#pragma unroll
        for (int mi = 0; mi < MFR; ++mi)
#pragma unroll
          for (int ni = 0; ni < 2; ++ni)
            acc[mi][ni] = mfma16(af[mi], bf_[ni], acc[mi][ni]);
      }
    }
    __syncthreads();
    cur ^= 1;
  }

  if (vsec) {
    // swapped acc: D rows = E-dim, cols = tokens -> vt (B,E,L)
    const int vbase = (MODE == 3) ? 1024 : 512;
    const int e0 = bn64 - vbase;
#pragma unroll
    for (int ni = 0; ni < 2; ++ni) {
#pragma unroll
      for (int r = 0; r < 4; ++r) {
        const int e = e0 + wc * 32 + ni * 16 + g * 4 + r;
        const float bv = HAS_BIAS ? bias[vbase + e] : 0.f;
#pragma unroll
        for (int mi = 0; mi < MFR; ++mi) {
          const int m = bm + wr * WM + mi * 16 + c;
          const int bb = m >> 9, lt = m & 511;
          C2[((size_t)bb * 512 + e) * 512 + lt] = f2b(acc[mi][ni][r] + bv);
        }
      }
    }
  } else {
    ushort* dst = C0;
    int nsub = 0, ldc = N;
    if (MODE == 3 || MODE == 5) {
      dst = (MODE == 5) ? C1 : (sec == 0 ? C0 : (sec == 1 ? C1 : C3));
      nsub = sec * 512;
      ldc = 512;
    }
#pragma unroll
    for (int ni = 0; ni < 2; ++ni) {
      const int n = bn64 + wc * 32 + ni * 16 + c;
      const float bv = HAS_BIAS ? bias[n] : 0.f;
#pragma unroll
      for (int mi = 0; mi < MFR; ++mi) {
#pragma unroll
        for (int r = 0; r < 4; ++r) {
          const int m = bm + wr * WM + mi * 16 + g * 4 + r;
          float v = acc[mi][ni][r] + bv;
          if (ACT) v = fmaxf(v, 0.f);
          dst[(size_t)m * ldc + (n - nsub)] = f2b(v);
        }
      }
    }
  }
}

// ---------------- attention core: aexp = (c_p/l) * sum exp(QK^T/8) V --------
__device__ __forceinline__ void dev_attn(ushort* lds, int bidx,
                                         const ushort* __restrict__ Qg,
                                         const ushort* __restrict__ Kg,
                                         const ushort* __restrict__ Vt,
                                         float c_p, ushort* __restrict__ aexp) {
  ushort* Qs = lds;           // 4096
  ushort* Ps = lds + 4096;    // 4096
  ushort* Ks = lds + 8192;    // 2 x 4096
  ushort* Vs = lds + 16384;   // 2 x 4096
  const int qt = 7 - (bidx & 7);  // heavy tiles dispatch first
  const int h = (bidx >> 3) & 7;
  const int b = bidx >> 6;
  const int tid = threadIdx.x, l = tid & 63, w = tid >> 6;
  const int g = l >> 4, c = l & 15;
  const int qrow0 = b * L + qt * 64;
  const ushort* Kbase = Kg + (size_t)(b * L) * E + h * 64;
  const ushort* Vbase = Vt + (size_t)(b * E + h * 64) * L;

  stage64<64>(Qg + (size_t)qrow0 * E + h * 64, E, Qs, tid);
  stage64<64>(Kbase, E, Ks, tid);
  stage64<64>(Vbase, L, Vs, tid);
  __syncthreads();

  f32x4 o[4];
#pragma unroll
  for (int dn = 0; dn < 4; ++dn) o[dn] = f32x4{0.f, 0.f, 0.f, 0.f};
  float l_r[4] = {0.f, 0.f, 0.f, 0.f};

  int cur = 0;
  for (int kt = 0; kt <= qt; ++kt) {
    if (kt < qt) {
      stage64<64>(Kbase + (size_t)(kt + 1) * 64 * E, E, Ks + (cur ^ 1) * 4096, tid);
      stage64<64>(Vbase + (kt + 1) * 64, L, Vs + (cur ^ 1) * 4096, tid);
    }
    bf16x8 qf[2];
#pragma unroll
    for (int kq = 0; kq < 2; ++kq) {
      int row = w * 16 + c;
      qf[kq] = *(const bf16x8*)(&Qs[row * 64 + (((kq * 4 + g) ^ (row & 7)) * 8)]);
    }
    f32x4 s4[4];
#pragma unroll
    for (int n = 0; n < 4; ++n) s4[n] = f32x4{0.f, 0.f, 0.f, 0.f};
#pragma unroll
    for (int n = 0; n < 4; ++n) {
#pragma unroll
      for (int kq = 0; kq < 2; ++kq) {
        int row = n * 16 + c;
        bf16x8 kf = *(const bf16x8*)(&Ks[cur * 4096 + row * 64 +
                                         (((kq * 4 + g) ^ (row & 7)) * 8)]);
        s4[n] = mfma16(qf[kq], kf, s4[n]);
      }
    }
    // P = exp(S/8), no max subtraction (|S/8| bounded; masked -> 0)
    const bool diag = (kt == qt);
    float pv[4][4];
    float lad[4] = {0.f, 0.f, 0.f, 0.f};
#pragma unroll
    for (int n = 0; n < 4; ++n)
#pragma unroll
      for (int r = 0; r < 4; ++r) {
        float sv = s4[n][r] * 0.125f;
        if (diag && (n * 16 + c) > (w * 16 + g * 4 + r)) sv = -1e30f;
        float p = __expf(sv);
        pv[n][r] = p;
        lad[r] += p;
      }
#pragma unroll
    for (int off = 1; off < 16; off <<= 1)
#pragma unroll
      for (int r = 0; r < 4; ++r) lad[r] += __shfl_xor(lad[r], off);
#pragma unroll
    for (int r = 0; r < 4; ++r) l_r[r] += lad[r];
#pragma unroll
    for (int n = 0; n < 4; ++n)
#pragma unroll
      for (int r = 0; r < 4; ++r) {
        int q = w * 16 + g * 4 + r;
        int byt = 32 * n + 2 * c;
        int slot = byt >> 4;
        Ps[q * 64 + ((slot ^ (q & 7)) * 8) + ((byt & 15) >> 1)] = f2b(pv[n][r]);
      }
    bf16x8 pf[2];
#pragma unroll
    for (int kq = 0; kq < 2; ++kq) {
      int row = w * 16 + c;
      pf[kq] = *(const bf16x8*)(&Ps[row * 64 + (((kq * 4 + g) ^ (row & 7)) * 8)]);
    }
#pragma unroll
    for (int dn = 0; dn < 4; ++dn) {
#pragma unroll
      for (int kq = 0; kq < 2; ++kq) {
        int row = dn * 16 + c;
        bf16x8 vf = *(const bf16x8*)(&Vs[cur * 4096 + row * 64 +
                                         (((kq * 4 + g) ^ (row & 7)) * 8)]);
        o[dn] = mfma16(pf[kq], vf, o[dn]);
      }
    }
    __syncthreads();
    cur ^= 1;
  }

  float linv[4];
#pragma unroll
  for (int r = 0; r < 4; ++r) linv[r] = c_p / l_r[r];
#pragma unroll
  for (int dn = 0; dn < 4; ++dn) {
#pragma unroll
    for (int r = 0; r < 4; ++r) {
      const size_t row = (size_t)qrow0 + w * 16 + g * 4 + r;
      const int col = h * 64 + dn * 16 + c;
      aexp[row * E + col] = f2b(o[dn][r] * linv[r]);
    }
  }
}

// ---------------- static blend row (wave per (b,q) row) --------------------
__device__ __forceinline__ void dev_blend(int idx, const float* __restrict__ rel,
                                          const float* __restrict__ resp,
                                          const float* __restrict__ ts,
                                          float l1, float l2, float l3,
                                          ushort* __restrict__ stat) {
  const float c_t = (1.f - l3) * (1.f - l1) * l2;
  const float c_r = (1.f - l3) * l1;
  const float c_s = l3;
  const int wave = threadIdx.x >> 6, lane = threadIdx.x & 63;
  const int row = idx * 4 + wave;
  const int qi = row & (L - 1);
  const size_t base = (size_t)row * L;
  float rv[8], sv[8], tv[8];
#pragma unroll
  for (int jj = 0; jj < 8; ++jj) {
    const int k = jj * 64 + lane;
    const float r = rel[base + k];
    const float s = resp[base + k];
    const float tt = ts[base + k];
    const bool fut = (k > qi);
    const float rm = fut ? r : 0.f;
    const float sm = fut ? s : 0.f;
    rv[jj] = (rm == 0.f) ? -1e4f : rm;
    sv[jj] = (sm == 0.f) ? -1e4f : sm;
    tv[jj] = fut ? -INFINITY : __expf(-fabsf(tt));
  }
  float rmax = -INFINITY, smax = -INFINITY, tmax = -INFINITY;
#pragma unroll
  for (int jj = 0; jj < 8; ++jj) {
    rmax = fmaxf(rmax, rv[jj]); smax = fmaxf(smax, sv[jj]); tmax = fmaxf(tmax, tv[jj]);
  }
  for (int off = 1; off < 64; off <<= 1) {
    rmax = fmaxf(rmax, __shfl_xor(rmax, off));
    smax = fmaxf(smax, __shfl_xor(smax, off));
    tmax = fmaxf(tmax, __shfl_xor(tmax, off));
  }
  float rsum = 0.f, ssum = 0.f, tsum = 0.f;
#pragma unroll
  for (int jj = 0; jj < 8; ++jj) {
    rsum += __expf(rv[jj] - rmax); ssum += __expf(sv[jj] - smax); tsum += __expf(tv[jj] - tmax);
  }
  for (int off = 1; off < 64; off <<= 1) {
    rsum += __shfl_xor(rsum, off);
    ssum += __shfl_xor(ssum, off);
    tsum += __shfl_xor(tsum, off);
  }
  const float rinv = c_r / rsum, sinv = c_s / ssum, tinv = c_t / tsum;
#pragma unroll
  for (int jj = 0; jj < 8; ++jj) {
    stat[base + jj * 64 + lane] =
        f2b(__expf(rv[jj] - rmax) * rinv + __expf(sv[jj] - smax) * sinv +
            __expf(tv[jj] - tmax) * tinv);
  }
}

// ======== launch 1: converts + weight transposes ===========================
__device__ __forceinline__ void tcvt_body(const float* __restrict__ src,
                                          ushort* __restrict__ dst, int Kd, int Nd,
                                          int kb, int nb, int t, ushort (*T)[33]) {
  const int r = t >> 3, c4 = (t & 7) * 4;
  float4 v = *(const float4*)(src + (size_t)(kb + r) * Nd + nb + c4);
  T[r][c4 + 0] = f2b(v.x); T[r][c4 + 1] = f2b(v.y);
  T[r][c4 + 2] = f2b(v.z); T[r][c4 + 3] = f2b(v.w);
  __syncthreads();
  ushort4 ov = {T[c4 + 0][r], T[c4 + 1][r], T[c4 + 2][r], T[c4 + 3][r]};
  *(ushort4*)(&dst[(size_t)(nb + r) * Kd + kb + c4]) = ov;
}

__global__ __launch_bounds__(256) void k_prep(
    const float* __restrict__ x4e, const float* __restrict__ query,
    const float* __restrict__ Win, const float* __restrict__ Wqkv,
    const float* __restrict__ Wf1, ushort* __restrict__ x4e_bf,
    ushort* __restrict__ qbf, ushort* __restrict__ Wint,
    ushort* __restrict__ Wqkvt, ushort* __restrict__ Wf1t) {
  __shared__ ushort T[32][33];
  const int NB_CVT = (M * 2048 / 4 + M * 512 / 4) / 256;  // 10240
  const int bi = blockIdx.x;
  const int t = threadIdx.x;
  if (bi < NB_CVT) {
    const int N1 = M * 2048 / 4;
    int i = bi * 256 + t;
    if (i < N1) {
      float4 v = ((const float4*)x4e)[i];
      ushort4 o = {f2b(v.x), f2b(v.y), f2b(v.z), f2b(v.w)};
      ((ushort4*)x4e_bf)[i] = o;
    } else {
      int j = i - N1;
      float4 v = ((const float4*)query)[j];
      ushort4 o = {f2b(v.x), f2b(v.y), f2b(v.z), f2b(v.w)};
      ((ushort4*)qbf)[j] = o;
    }
    return;
  }
  const int idx = bi - NB_CVT;
  const long long EE = (long long)E * E;
  if (idx < 1024) {
    tcvt_body(Win, Wint, 2048, 512, (idx >> 4) * 32, (idx & 15) * 32, t, T);
  } else if (idx < 2560) {
    const int q = idx - 1024;
    const int z = q >> 8, r = q & 255;
    tcvt_body(Wqkv + z * EE, Wqkvt + z * EE, 512, 512, (r >> 4) * 32, (r & 15) * 32, t, T);
  } else {
    const int q = idx - 2560;
    tcvt_body(Wf1, Wf1t, 1024, 512, (q >> 4) * 32, (q & 15) * 32, t, T);
  }
}

// ======== launch 2: x-GEMM (512 blocks) ∥ static blend (1024 blocks) =======
__global__ __launch_bounds__(256) void k_xgemm_blend(
    const ushort* __restrict__ x4e_bf, const ushort* __restrict__ Wint,
    const float* __restrict__ b_in, ushort* __restrict__ x_bf,
    const float* __restrict__ rel, const float* __restrict__ resp,
    const float* __restrict__ ts, const float* __restrict__ l1p,
    const float* __restrict__ l2p, const float* __restrict__ l3p,
    ushort* __restrict__ stat) {
  extern __shared__ ushort lds[];
  const int bx = blockIdx.x;
  if (bx < 512) {
    dev_gemm<64, 1, 1, 1, 0>(lds, bx & 7, bx >> 3, x4e_bf, nullptr, nullptr,
                             nullptr, nullptr, Wint, b_in, x_bf, nullptr,
                             nullptr, nullptr, 2048, 512);
  } else {
    dev_blend(bx - 512, rel, resp, ts, l1p[0], l2p[0], l3p[0], stat);
  }
}

// ======== launch 3: qkv0 + hoisted q1 ======================================
__global__ __launch_bounds__(256) void k_qkv0(
    const ushort* __restrict__ query_bf, const ushort* __restrict__ x_bf,
    const ushort* __restrict__ Wqkvt, const float* __restrict__ bqkv,
    ushort* __restrict__ q_bf, ushort* __restrict__ k_bf,
    ushort* __restrict__ vt, ushort* __restrict__ q1_bf) {
  extern __shared__ ushort lds[];
  dev_gemm<128, 3, 1, 0, 0>(lds, blockIdx.x, blockIdx.y, query_bf, x_bf, nullptr,
                            nullptr, nullptr, Wqkvt, bqkv, q_bf, k_bf, vt, q1_bf,
                            512, 2048);
}

// ======== launch 4/6: attention (512) ∥ stat-GEMM (512) ====================
__global__ __launch_bounds__(256) void k_attn_stat(
    const ushort* __restrict__ Qg, const ushort* __restrict__ Kg,
    const ushort* __restrict__ Vt, const ushort* __restrict__ stat,
    const float* __restrict__ l1p, const float* __restrict__ l2p,
    const float* __restrict__ l3p, ushort* __restrict__ aexp,
    ushort* __restrict__ ostat) {
  extern __shared__ ushort lds[];
  const int bx = blockIdx.x;
  if (bx < 512) {
    const float l1 = l1p[0], l2 = l2p[0], l3 = l3p[0];
    const float c_p = (1.f - l3) * (1.f - l1) * (1.f - l2);
    dev_attn(lds, bx, Qg, Kg, Vt, c_p, aexp);
  } else {
    const int idx = bx - 512;
    const int bz = idx >> 6, r = idx & 63;
    const long long LLs = (long long)L * L, ELs = (long long)E * L;
    dev_gemm<64, 1, 0, 0, 0>(lds, r & 7, r >> 3, stat + bz * LLs, nullptr,
                             nullptr, nullptr, nullptr, Vt + bz * ELs, nullptr,
                             ostat + bz * ELs, nullptr, nullptr, nullptr, 512, 512);
  }
}

// ======== launch 5: layer-1 k,v with A = aexp0+ostat0 ======================
__global__ __launch_bounds__(256) void k_kv1(
    const ushort* __restrict__ aexp0, const ushort* __restrict__ ostat0,
    const ushort* __restrict__ Wt, const float* __restrict__ bias,
    ushort* __restrict__ k_bf, ushort* __restrict__ vt) {
  extern __shared__ ushort lds[];
  dev_gemm<128, 5, 1, 0, 2>(lds, blockIdx.x, blockIdx.y, aexp0, ostat0, nullptr,
                            nullptr, nullptr, Wt, bias, nullptr, k_bf, vt,
                            nullptr, 512, 1024);
}

// ======== launch 7: f1 with A-left = (aexp0+ostat0)+relu(aexp1+ostat1) =====
__global__ __launch_bounds__(256) void k_f1(
    const ushort* __restrict__ aexp0, const ushort* __restrict__ ostat0,
    const ushort* __restrict__ aexp1, const ushort* __restrict__ ostat1,
    const ushort* __restrict__ query_bf, const ushort* __restrict__ Wf1t,
    const float* __restrict__ bf1, ushort* __restrict__ h_bf) {
  extern __shared__ ushort lds[];
  dev_gemm<64, 4, 1, 1, 4>(lds, blockIdx.x, blockIdx.y, aexp0, ostat0, aexp1,
                           ostat1, query_bf, Wf1t, bf1, h_bf, nullptr, nullptr,
                           nullptr, 1024, 512);
}

// ======== launch 8: out[m] = h[m,:].Wf2 + bf2 ==============================
__global__ __launch_bounds__(256) void final_dot_kernel(
    const ushort* __restrict__ hb, const float* __restrict__ w,
    const float* __restrict__ b2, float* __restrict__ out) {
  const int m = blockIdx.x * 4 + (threadIdx.x >> 6);
  const int lane = threadIdx.x & 63;
  float s = 0.f;
#pragma unroll
  for (int it = 0; it < 2; ++it) {
    const int e = it * 256 + lane * 4;
    ushort4 hv = *(const ushort4*)(hb + (size_t)m * E + e);
    float4 wv = *(const float4*)(w + e);
    s += b2f(hv.x) * wv.x + b2f(hv.y) * wv.y + b2f(hv.z) * wv.z + b2f(hv.w) * wv.w;
  }
  for (int off = 1; off < 64; off <<= 1) s += __shfl_xor(s, off);
  if (lane == 0) out[m] = s + b2[0];
}

extern "C" void kernel_launch(void* const* d_in, const int* in_sizes, int n_in,
                              void* d_out, int out_size, void* d_ws, size_t ws_size,
                              hipStream_t stream) {
  (void)in_sizes; (void)n_in; (void)out_size; (void)ws_size;
  const float* inputs_4e = (const float*)d_in[0];
  const float* query = (const float*)d_in[1];
  const float* rel = (const float*)d_in[2];
  const float* resp = (const float*)d_in[3];
  const float* tsp = (const float*)d_in[4];
  const float* l1p = (const float*)d_in[5];
  const float* l2p = (const float*)d_in[6];
  const float* l3p = (const float*)d_in[7];
  const float* Win = (const float*)d_in[8];
  const float* b_in = (const float*)d_in[9];
  const float* Wqkv = (const float*)d_in[10];
  const float* bqkv = (const float*)d_in[11];
  const float* Wf1 = (const float*)d_in[12];
  const float* bf1 = (const float*)d_in[13];
  const float* Wf2 = (const float*)d_in[14];
  const float* bf2 = (const float*)d_in[15];

  char* ws = (char*)d_ws;
  const size_t MB = 1ull << 20;
  ushort* x4e_bf  = (ushort*)(ws + 0 * MB);   // 16MB; dead after launch 2
  ushort* aexp0   = (ushort*)(ws + 0 * MB);   // 4MB (written launch 4)
  ushort* ostat0  = (ushort*)(ws + 4 * MB);   // 4MB (written launch 4)
  ushort* aexp1   = (ushort*)(ws + 8 * MB);   // 4MB (written launch 6)
  ushort* ostat1  = (ushort*)(ws + 12 * MB);  // 4MB (written launch 6)
  ushort* query_bf= (ushort*)(ws + 16 * MB);  // 4MB
  ushort* stat_bf = (ushort*)(ws + 20 * MB);  // 4MB
  ushort* x_bf    = (ushort*)(ws + 24 * MB);  // 4MB; dead after qkv0 -> h_bf
  ushort* h_bf    = (ushort*)(ws + 24 * MB);
  ushort* q_bf    = (ushort*)(ws + 28 * MB);  // 4MB
  ushort* k_bf    = (ushort*)(ws + 32 * MB);  // 4MB
  ushort* vt      = (ushort*)(ws + 36 * MB);  // 4MB (B,E,L)
  ushort* q1_bf   = (ushort*)(ws + 40 * MB);  // 4MB
  ushort* Wint    = (ushort*)(ws + 48 * MB);  // 2MB
  ushort* Wqkvt   = (ushort*)(ws + 50 * MB);  // 3MB
  ushort* Wf1t    = (ushort*)(ws + 53 * MB);  // 1MB

  const long long EE = (long long)E * E;
  const int LDS_G64 = (2 * 64 * 64 + 2 * 64 * 64) * 2;      // 32768
  const int LDS_G128 = (2 * 128 * 64 + 2 * 64 * 64) * 2;    // 49152
  const int LDS_AS = 49152;                                  // attn 48K / gemm 32K

  // 1) converts + weight transposes
  k_prep<<<10240 + 3072, 256, 0, stream>>>(inputs_4e, query, Win, Wqkv, Wf1,
                                           x4e_bf, query_bf, Wint, Wqkvt, Wf1t);
  // 2) x-GEMM ∥ static blend
  k_xgemm_blend<<<512 + 1024, 256, LDS_G64, stream>>>(
      x4e_bf, Wint, b_in, x_bf, rel, resp, tsp, l1p, l2p, l3p, stat_bf);
  // 3) qkv0 + q1
  k_qkv0<<<dim3(32, 32), 256, LDS_G128, stream>>>(query_bf, x_bf, Wqkvt, bqkv,
                                                  q_bf, k_bf, vt, q1_bf);
  // 4) attn0 ∥ stat0
  k_attn_stat<<<1024, 256, LDS_AS, stream>>>(q_bf, k_bf, vt, stat_bf,
                                             l1p, l2p, l3p, aexp0, ostat0);
  // 5) layer-1 k,v (A = aexp0 + ostat0)
  k_kv1<<<dim3(16, 32), 256, LDS_G128, stream>>>(aexp0, ostat0, Wqkvt + 4 * EE,
                                                 bqkv + 4 * E, k_bf, vt);
  // 6) attn1 ∥ stat1
  k_attn_stat<<<1024, 256, LDS_AS, stream>>>(q1_bf, k_bf, vt, stat_bf,
                                             l1p, l2p, l3p, aexp1, ostat1);
  // 7) h = relu([outs2 | query] @ Wf1 + bf1), outs2 built in staging
  k_f1<<<dim3(8, 64), 256, LDS_G64, stream>>>(aexp0, ostat0, aexp1, ostat1,
                                              query_bf, Wf1t, bf1, h_bf);
  // 8) out = h @ Wf2 + bf2
  final_dot_kernel<<<M / 4, 256, 0, stream>>>(h_bf, Wf2, bf2, (float*)d_out);
}